// Round 11
// baseline (44.923 us; speedup 1.0000x reference)
//
#include <hip/hip_runtime.h>
#include <stdint.h>

#define MROWS 131072
#define NSPEC 8
#define DIN   128
#define NOUT  256
#define BM    256                    // natural rows per block (block-local sort)

typedef __attribute__((ext_vector_type(8))) short s16x8;
typedef __attribute__((ext_vector_type(4))) float f32x4;

// workspace: only the bf16 fragment-ordered W
#define OFF_BF    ((size_t)0)        // 8*16*4*1024 = 524288 B
#define WS_NEEDED ((size_t)524288)

__device__ __forceinline__ uint32_t bf16_1(float f) {
  union { float f; uint32_t u; } v; v.f = f;
  return (v.u + 0x7FFFu + ((v.u >> 16) & 1u)) >> 16;  // RNE, inputs finite
}

// Convert W [8][128][256] fp32 -> bf16 fragment order (R10 col-interleaved
// mapping, unchanged): chunk c = ((s*16 + f)*4 + kt), f = w*4 + ni;
// n = (f>>2)*64 + (l&15)*4 + (f&3); lane l holds B[k = kt*32+(l>>4)*8+j][n].
__global__ void k_convert(const float* __restrict__ B, char* __restrict__ ws) {
  int gid = blockIdx.x * 256 + threadIdx.x;   // 32768 threads
  int l  = gid & 63;
  int c  = gid >> 6;                          // 0..511
  int kt = c & 3;
  int f  = (c >> 2) & 15;
  int s  = c >> 6;
  int n  = (f >> 2) * 64 + (l & 15) * 4 + (f & 3);
  int k0 = kt * 32 + (l >> 4) * 8;
  const float* src = B + (size_t)s * DIN * NOUT + n;
  uint32_t w0 = bf16_1(src[(size_t)(k0 + 0) * NOUT]) | (bf16_1(src[(size_t)(k0 + 1) * NOUT]) << 16);
  uint32_t w1 = bf16_1(src[(size_t)(k0 + 2) * NOUT]) | (bf16_1(src[(size_t)(k0 + 3) * NOUT]) << 16);
  uint32_t w2 = bf16_1(src[(size_t)(k0 + 4) * NOUT]) | (bf16_1(src[(size_t)(k0 + 5) * NOUT]) << 16);
  uint32_t w3 = bf16_1(src[(size_t)(k0 + 6) * NOUT]) | (bf16_1(src[(size_t)(k0 + 7) * NOUT]) << 16);
  *(uint4*)(ws + OFF_BF + (size_t)c * 1024 + (size_t)l * 16) = make_uint4(w0, w1, w2, w3);
}

// raw barrier that does NOT drain vmcnt (keeps next-chunk A-loads in flight);
// lgkmcnt(0) makes our ds_writes visible, sched_barrier stops read hoisting.
__device__ __forceinline__ void bar_keep_vmem() {
  asm volatile("s_waitcnt lgkmcnt(0)" ::: "memory");
  __builtin_amdgcn_s_barrier();
  __builtin_amdgcn_sched_barrier(0);
}

// Sort-free grouped GEMM with chunked async staging (T14):
// one block = 256 natural rows x 256 cols, 4 waves, 2 blocks/CU.
// Chunks of 64 slots double-buffer through register sets ra/rb; each chunk's
// A-loads are issued right after a barrier and retire under the previous
// chunk's MFMA + store drain.
__global__ __launch_bounds__(256, 2) void k_gemm_ns(const float* __restrict__ A,
                                                    const int* __restrict__ sp,
                                                    const char* __restrict__ ws,
                                                    float* __restrict__ out) {
  const char* Bf = ws + OFF_BF;
  __shared__ char As[BM * 256];     // 64 KB: [slot][128 k] bf16, XOR-swizzled
  __shared__ int invOf[BM];         // slot -> natural row (in-block)
  __shared__ int cnt[NSPEC];
  __shared__ int gstart[NSPEC + 1];

  int t = threadIdx.x;
  int base = blockIdx.x * BM;

  // ---- block-local counting sort of 256 rows by species
  if (t < NSPEC) cnt[t] = 0;
  __syncthreads();
  int s_r = sp[base + t] & 7;                 // thread t owns natural row t
  int rank = atomicAdd(&cnt[s_r], 1);
  __syncthreads();
  if (t == 0) {
    int a = 0;
    #pragma unroll
    for (int j = 0; j < NSPEC; ++j) { gstart[j] = a; a += cnt[j]; }
    gstart[NSPEC] = a;                        // == BM
  }
  __syncthreads();
  invOf[gstart[s_r] + rank] = t;
  __syncthreads();                            // invOf/gstart stable from here

  int f4 = t & 31;                            // 32 lanes per row (float4 each)
  int r8 = t >> 5;                            // 8 slot-rows per chunk-iter
  int w = t >> 6, l = t & 63;
  int colBase = w * 64 + (l & 15) * 4;        // col-interleaved store base

  float4 ra[8], rb[8];
  s16x8 bfr[4][4];                            // current species' B-frags
  int cur = -1;

  // issue chunk-c A-loads in slot order (512B-row gathers, coalesced)
  auto LD = [&](float4 (&reg)[8], int c) {
    #pragma unroll
    for (int j = 0; j < 8; ++j) {
      int slot = c * 64 + r8 + j * 8;
      int row = invOf[slot];
      reg[j] = *(const float4*)(A + (size_t)(base + row) * DIN + f4 * 4);
    }
  };
  // cvt + LDS write (waits only this set's loads via register dependency)
  auto WR = [&](float4 (&reg)[8], int c) {
    #pragma unroll
    for (int j = 0; j < 8; ++j) {
      int slot = c * 64 + r8 + j * 8;
      uint32_t lo = bf16_1(reg[j].x) | (bf16_1(reg[j].y) << 16);
      uint32_t hi = bf16_1(reg[j].z) | (bf16_1(reg[j].w) << 16);
      int off = (slot * 256 + f4 * 8) ^ ((slot & 7) << 4);   // G4 swizzle
      *(uint2*)(As + off) = make_uint2(lo, hi);
    }
  };
  // compute chunk c: subtiles 4c..4c+3, species segments, predicated stores
  auto CMP = [&](int c) {
    for (int st = c * 4; st < c * 4 + 4; ++st) {
      int r16 = st * 16;
      int slo = 0, shi = 0;
      #pragma unroll
      for (int j = 1; j < NSPEC; ++j) {       // species of first/last slot
        if (r16 >= gstart[j]) slo = j;
        if (r16 + 15 >= gstart[j]) shi = j;
      }
      for (int s = slo; s <= shi; ++s) {      // wave-uniform
        int gs = gstart[s], ge = gstart[s + 1];
        if (ge <= gs) continue;
        if (s != cur) {                       // monotone -> ~8 loads total
          cur = s;
          #pragma unroll
          for (int ni = 0; ni < 4; ++ni)
            #pragma unroll
            for (int kt = 0; kt < 4; ++kt)
              bfr[ni][kt] = *(const s16x8*)(Bf +
                  (size_t)((s * 16 + (w * 4 + ni)) * 4 + kt) * 1024 + (size_t)l * 16);
        }
        f32x4 acc[4];
        #pragma unroll
        for (int ni = 0; ni < 4; ++ni) acc[ni] = (f32x4){0.f, 0.f, 0.f, 0.f};
        #pragma unroll
        for (int kt = 0; kt < 4; ++kt) {
          int rr = r16 + (l & 15);
          int off = (rr * 256 + kt * 64 + (l >> 4) * 16) ^ ((rr & 7) << 4);
          s16x8 afr = *(const s16x8*)(As + off);
          #pragma unroll
          for (int ni = 0; ni < 4; ++ni)
            acc[ni] = __builtin_amdgcn_mfma_f32_16x16x32_bf16(afr, bfr[ni][kt], acc[ni], 0, 0, 0);
        }
        #pragma unroll
        for (int q = 0; q < 4; ++q) {         // predicated float4 stores
          int slotrow = r16 + ((l >> 4) << 2) + q;
          if (slotrow >= gs && slotrow < ge) {
            int rid = base + invOf[slotrow];
            float4 v4 = make_float4(acc[0][q], acc[1][q], acc[2][q], acc[3][q]);
            *(float4*)(out + (size_t)rid * NOUT + colBase) = v4;
          }
        }
      }
    }
  };

  // ---- software-pipelined chunk schedule (regions disjoint per chunk)
  LD(ra, 0);
  LD(rb, 1);
  WR(ra, 0); bar_keep_vmem();
  LD(ra, 2);                                  // flies under CMP(0)
  CMP(0);
  WR(rb, 1); bar_keep_vmem();
  LD(rb, 3);                                  // flies under CMP(1)
  CMP(1);
  WR(ra, 2); bar_keep_vmem();
  CMP(2);
  WR(rb, 3); bar_keep_vmem();
  CMP(3);
}

// ws-free correctness fallback (only if ws_size is unexpectedly small)
__global__ void k_naive(const float* __restrict__ A, const int* __restrict__ sp,
                        const float* __restrict__ B, float* __restrict__ out) {
  __shared__ float av[DIN];
  int m = blockIdx.x;
  int n = threadIdx.x;
  if (n < DIN) av[n] = A[(size_t)m * DIN + n];
  __syncthreads();
  int s = sp[m] & 7;
  const float* b = B + (size_t)s * DIN * NOUT + n;
  float acc = 0.f;
  #pragma unroll 8
  for (int k = 0; k < DIN; ++k) acc = fmaf(av[k], b[(size_t)k * NOUT], acc);
  out[(size_t)m * NOUT + n] = acc;
}

extern "C" void kernel_launch(void* const* d_in, const int* in_sizes, int n_in,
                              void* d_out, int out_size, void* d_ws, size_t ws_size,
                              hipStream_t stream) {
  const float* values = (const float*)d_in[0];
  const int*   sp     = (const int*)d_in[1];
  const float* B      = (const float*)d_in[2];
  float*       out    = (float*)d_out;

  if (d_ws == nullptr || ws_size < WS_NEEDED) {
    k_naive<<<MROWS, NOUT, 0, stream>>>(values, sp, B, out);
    return;
  }
  char* ws = (char*)d_ws;
  k_convert<<<128, 256, 0, stream>>>(B, ws);
  k_gemm_ns<<<MROWS / BM, 256, 0, stream>>>(values, sp, ws, out);
}

// Round 12
// 43.872 us; speedup vs baseline: 1.0240x; 1.0240x over previous
//
#include <hip/hip_runtime.h>
#include <stdint.h>

#define MROWS 131072
#define NSPEC 8
#define DIN   128
#define NOUT  256
#define BM    256                    // natural rows per block (block-local sort)
#define NTHR  512                    // 8 waves; each wave owns a 32-col strip

typedef __attribute__((ext_vector_type(8))) short s16x8;
typedef __attribute__((ext_vector_type(4))) float f32x4;

// workspace: only the bf16 fragment-ordered W
#define OFF_BF    ((size_t)0)        // 8*16*4*1024 = 524288 B
#define WS_NEEDED ((size_t)524288)

__device__ __forceinline__ uint32_t bf16_1(float f) {
  union { float f; uint32_t u; } v; v.f = f;
  return (v.u + 0x7FFFu + ((v.u >> 16) & 1u)) >> 16;  // RNE, inputs finite
}

// Convert W [8][128][256] fp32 -> bf16 fragment order, 32-COL-STRIP mapping:
// chunk c = ((s*16 + f)*4 + kt); wave w uses f in {2w, 2w+1} (ni = f&1).
// lane l holds B[k = kt*32 + (l>>4)*8 + j][n], j=0..7, with
//   n = (f>>1)*32 + (l&15)*2 + (f&1)
// so D-fragment ni, lane m covers global col w*32 + m*2 + ni -> a lane's two
// ni-values are 2 consecutive floats (float2 epilogue stores).
__global__ void k_convert(const float* __restrict__ B, char* __restrict__ ws) {
  int gid = blockIdx.x * 256 + threadIdx.x;   // 32768 threads
  int l  = gid & 63;
  int c  = gid >> 6;                          // 0..511
  int kt = c & 3;
  int f  = (c >> 2) & 15;
  int s  = c >> 6;
  int n  = (f >> 1) * 32 + (l & 15) * 2 + (f & 1);
  int k0 = kt * 32 + (l >> 4) * 8;
  const float* src = B + (size_t)s * DIN * NOUT + n;
  uint32_t w0 = bf16_1(src[(size_t)(k0 + 0) * NOUT]) | (bf16_1(src[(size_t)(k0 + 1) * NOUT]) << 16);
  uint32_t w1 = bf16_1(src[(size_t)(k0 + 2) * NOUT]) | (bf16_1(src[(size_t)(k0 + 3) * NOUT]) << 16);
  uint32_t w2 = bf16_1(src[(size_t)(k0 + 4) * NOUT]) | (bf16_1(src[(size_t)(k0 + 5) * NOUT]) << 16);
  uint32_t w3 = bf16_1(src[(size_t)(k0 + 6) * NOUT]) | (bf16_1(src[(size_t)(k0 + 7) * NOUT]) << 16);
  *(uint4*)(ws + OFF_BF + (size_t)c * 1024 + (size_t)l * 16) = make_uint4(w0, w1, w2, w3);
}

// Grouped GEMM, block-local sort, 8 waves x 32-col strips (occupancy lever):
// LDS 64KB -> 2 blocks/CU, but 16 waves/CU (50%) vs R10's 8 (22%).
__global__ __launch_bounds__(NTHR, 4) void k_gemm_ns(const float* __restrict__ A,
                                                     const int* __restrict__ sp,
                                                     const char* __restrict__ ws,
                                                     float* __restrict__ out) {
  const char* Bf = ws + OFF_BF;
  __shared__ char As[BM * 256];     // 64 KB: [slot][128 k] bf16, XOR-swizzled
  __shared__ int slotOf[BM];        // natural row (in-block) -> slot
  __shared__ int invOf[BM];         // slot -> natural row (in-block)
  __shared__ int cnt[NSPEC];
  __shared__ int gstart[NSPEC + 1];

  int t = threadIdx.x;
  int base = blockIdx.x * BM;

  // ---- block-local counting sort of 256 rows by species (threads 0..255)
  if (t < NSPEC) cnt[t] = 0;
  __syncthreads();
  if (t < BM) {
    int s_r = sp[base + t] & 7;               // thread t owns natural row t
    int rank = atomicAdd(&cnt[s_r], 1);
    slotOf[t] = rank;                         // temp: rank within species
  }
  __syncthreads();
  if (t == 0) {
    int a = 0;
    #pragma unroll
    for (int j = 0; j < NSPEC; ++j) { gstart[j] = a; a += cnt[j]; }
    gstart[NSPEC] = a;                        // == BM
  }
  __syncthreads();
  if (t < BM) {
    int s_r = sp[base + t] & 7;
    int myslot = gstart[s_r] + slotOf[t];
    slotOf[t] = myslot;
    invOf[myslot] = t;
  }
  __syncthreads();

  // ---- stage A: SEQUENTIAL global reads, LDS write at sorted slot
  int f4 = t & 31, r0 = t >> 5;               // 16 row-groups of 16 rows
  #pragma unroll
  for (int it = 0; it < 16; ++it) {
    int r = r0 + it * 16;
    float4 v = *(const float4*)(A + (size_t)(base + r) * DIN + f4 * 4);
    int sl = slotOf[r];                       // broadcast within 32-lane group
    uint32_t lo = bf16_1(v.x) | (bf16_1(v.y) << 16);
    uint32_t hi = bf16_1(v.z) | (bf16_1(v.w) << 16);
    int off = (sl * 256 + f4 * 8) ^ ((sl & 7) << 4);   // G4 swizzle
    *(uint2*)(As + off) = make_uint2(lo, hi);
  }
  __syncthreads();

  // ---- per-species MFMA over slot ranges (wave w: cols w*32 .. w*32+31)
  int w = t >> 6, l = t & 63;
  int colBase = w * 32 + (l & 15) * 2;        // col-interleaved layout
  for (int s = 0; s < NSPEC; ++s) {
    int gs = gstart[s], ge = gstart[s + 1];
    if (gs == ge) continue;
    // B fragments for this species & this wave's 32-col strip: 8 x 1KB from L2
    s16x8 bfr[2][4];                          // [ni][kt] -> 32 VGPR
    #pragma unroll
    for (int ni = 0; ni < 2; ++ni)
      #pragma unroll
      for (int kt = 0; kt < 4; ++kt) {
        int c = (s * 16 + (w * 2 + ni)) * 4 + kt;
        bfr[ni][kt] = *(const s16x8*)(Bf + (size_t)c * 1024 + (size_t)l * 16);
      }
    int st0 = gs >> 4, st1 = (ge - 1) >> 4;   // subtiles touching this group
    for (int st = st0; st <= st1; ++st) {
      f32x4 acc[2];
      #pragma unroll
      for (int ni = 0; ni < 2; ++ni) acc[ni] = (f32x4){0.f, 0.f, 0.f, 0.f};
      #pragma unroll
      for (int kt = 0; kt < 4; ++kt) {
        int r = st * 16 + (l & 15);
        int off = (r * 256 + kt * 64 + (l >> 4) * 16) ^ ((r & 7) << 4);
        s16x8 afr = *(const s16x8*)(As + off);
        #pragma unroll
        for (int ni = 0; ni < 2; ++ni)
          acc[ni] = __builtin_amdgcn_mfma_f32_16x16x32_bf16(afr, bfr[ni][kt], acc[ni], 0, 0, 0);
      }
      // predicated float2 store: lane's 2 ni-values are consecutive cols
      #pragma unroll
      for (int q = 0; q < 4; ++q) {
        int slotrow = st * 16 + ((l >> 4) << 2) + q;
        if (slotrow >= gs && slotrow < ge) {
          int rid = base + invOf[slotrow];    // broadcast within 16-lane group
          float2 v2 = make_float2(acc[0][q], acc[1][q]);
          *(float2*)(out + (size_t)rid * NOUT + colBase) = v2;
        }
      }
    }
  }
}

// ws-free correctness fallback (only if ws_size is unexpectedly small)
__global__ void k_naive(const float* __restrict__ A, const int* __restrict__ sp,
                        const float* __restrict__ B, float* __restrict__ out) {
  __shared__ float av[DIN];
  int m = blockIdx.x;
  int n = threadIdx.x;
  if (n < DIN) av[n] = A[(size_t)m * DIN + n];
  __syncthreads();
  int s = sp[m] & 7;
  const float* b = B + (size_t)s * DIN * NOUT + n;
  float acc = 0.f;
  #pragma unroll 8
  for (int k = 0; k < DIN; ++k) acc = fmaf(av[k], b[(size_t)k * NOUT], acc);
  out[(size_t)m * NOUT + n] = acc;
}

extern "C" void kernel_launch(void* const* d_in, const int* in_sizes, int n_in,
                              void* d_out, int out_size, void* d_ws, size_t ws_size,
                              hipStream_t stream) {
  const float* values = (const float*)d_in[0];
  const int*   sp     = (const int*)d_in[1];
  const float* B      = (const float*)d_in[2];
  float*       out    = (float*)d_out;

  if (d_ws == nullptr || ws_size < WS_NEEDED) {
    k_naive<<<MROWS, NOUT, 0, stream>>>(values, sp, B, out);
    return;
  }
  char* ws = (char*)d_ws;
  k_convert<<<128, 256, 0, stream>>>(B, ws);
  k_gemm_ns<<<MROWS / BM, NTHR, 0, stream>>>(values, sp, ws, out);
}